// Round 4
// baseline (2307.563 us; speedup 1.0000x reference)
//
#include <hip/hip_runtime.h>
#include <hip/hip_fp16.h>
#include <stdint.h>

#define SEQ   1024
#define BATCH 128
#define INDIM 256
#define HID   512
#define INV_TAU 0.1f

typedef _Float16 f16;
typedef _Float16 f16x2 __attribute__((ext_vector_type(2)));
typedef _Float16 f16x8 __attribute__((ext_vector_type(8)));
typedef float    f32x4 __attribute__((ext_vector_type(4)));

static __device__ __forceinline__ f16x2 pk2(float a, float b) {
  auto r = __builtin_amdgcn_cvt_pkrtz(a, b);
  union { decltype(r) i; f16x2 o; } u;
  u.i = r;
  return u.o;
}

// ---------------------------------------------------------------------------
// K1: A = x @ win + bias  -> written into d_out (in place; K2 overwrites with h)
// ---------------------------------------------------------------------------
__global__ __launch_bounds__(512, 2)
void k1_gemm(const float* __restrict__ x, const float* __restrict__ win,
             const float* __restrict__ bias, float* __restrict__ out) {
  __shared__ __align__(16) f16x2 b_lds[HID][20];

  const int tid  = threadIdx.x;
  const int lane = tid & 63;
  const int wid  = tid >> 6;
  const int wr2  = wid >> 2;
  const int wc   = wid & 3;
  const int l15  = lane & 15;
  const int kg   = lane >> 4;

  const long m0 = (long)blockIdx.x * 64;

  f32x4 acc[2][8];
  #pragma unroll
  for (int a = 0; a < 2; ++a)
    #pragma unroll
    for (int bq = 0; bq < 8; ++bq) acc[a][bq] = (f32x4){0.f, 0.f, 0.f, 0.f};

  const int sp0 = (tid >> 8) * 8;
  const int sn0 = tid & 255;

  for (int ks = 0; ks < 8; ++ks) {
    const int k0 = ks * 32;
    #pragma unroll
    for (int r = 0; r < 8; ++r) {
      const int p = sp0 + r;
      #pragma unroll
      for (int i = 0; i < 2; ++i) {
        const int n = sn0 + 256 * i;
        const float lo = win[(k0 + 2 * p) * HID + n];
        const float hi = win[(k0 + 2 * p + 1) * HID + n];
        const int g  = p >> 2;
        const int gs = g ^ (n & 3);
        b_lds[n][gs * 4 + (p & 3)] = pk2(lo, hi);
      }
    }
    __syncthreads();

    f16x8 af[2];
    #pragma unroll
    for (int mf = 0; mf < 2; ++mf) {
      const long row = m0 + wr2 * 32 + mf * 16 + l15;
      const float4* xp = (const float4*)(x + row * INDIM + k0 + kg * 8);
      const float4 a0 = xp[0];
      const float4 a1 = xp[1];
      union { f16x2 h2[4]; f16x8 h8; } u;
      u.h2[0] = pk2(a0.x, a0.y); u.h2[1] = pk2(a0.z, a0.w);
      u.h2[2] = pk2(a1.x, a1.y); u.h2[3] = pk2(a1.z, a1.w);
      af[mf] = u.h8;
    }

    #pragma unroll
    for (int nf = 0; nf < 8; ++nf) {
      const int n  = wc * 128 + nf * 16 + l15;
      const int gs = kg ^ (n & 3);
      union { uint4 v; f16x8 h8; } u;
      u.v = *(const uint4*)&b_lds[n][gs * 4];
      #pragma unroll
      for (int mf = 0; mf < 2; ++mf)
        acc[mf][nf] = __builtin_amdgcn_mfma_f32_16x16x32_f16(af[mf], u.h8, acc[mf][nf], 0, 0, 0);
    }
    __syncthreads();
  }

  #pragma unroll
  for (int nf = 0; nf < 8; ++nf) {
    const int col = wc * 128 + nf * 16 + l15;
    const float bc = bias[col];
    #pragma unroll
    for (int mf = 0; mf < 2; ++mf) {
      const long rowb = m0 + wr2 * 32 + mf * 16 + kg * 4;
      #pragma unroll
      for (int r = 0; r < 4; ++r)
        out[(rowb + r) * HID + col] = acc[mf][nf][r] + bc;
    }
  }
}

// ---------------------------------------------------------------------------
// K2: per-batch-row recurrence. 128 blocks x *** 1024 threads ***, 1 block/CU.
//
// WHY 1024 threads: rounds 0-3 all showed VGPR_Count=128 and
// OccupancyPercent ~12% (= 1 wave/SIMD).  Model: the allocator pins arch
// VGPRs at the 128 budget and overflows the 192 per-thread weight regs into
// AGPRs (gfx950 unified file) -> ~384 total regs/wave -> HW occupancy 1
// wave/SIMD -> every LDS/AGPR-copy/barrier latency fully exposed (~2900
// cy/step stall; VALUBusy 31%).  Attributes (launch_bounds min-waves,
// amdgpu_waves_per_eu) failed to move it 3 rounds in a row.
// With 1024 threads the per-thread weight footprint HALVES: 2 cols x 64
// k-pairs = 128 f16x2 -> 96 in registers + 32 in 128KB LDS; working set
// ~25 -> total ~125 <= 128 BY CONSTRUCTION.  16 waves/CU = 4 waves/SIMD:
// latency hiding restored, VALU floor 1024 cy/step/SIMD now reachable.
//
// thread: q = tid&3 -> k-slice [128q, 128q+128); jj = tid>>2 -> cols
// c0=2jj, c0+1.  Numerics identical to round-3 (4 slices x 64-pair f16x2
// chains + quad butterfly).
//
// h broadcast: hbuf = 2 x 64 uint4 lines, line-swizzled phys = (q*17)^i so
// the 4 q-groups of a wave hit disjoint bank groups (conflict-free).
// Weights LDS part: 8 planes of uint4[1024], plane p = self-owned slot
// w4[p*1024 + tid] -> lane-consecutive ds_read_b128, conflict-free, no
// barrier (same-thread RAW).  1 barrier per step.
// ---------------------------------------------------------------------------
#define K2_SMEM (131072 + 2048)

#define DECL_W(u) f16x2 W##u##_0, W##u##_1;

// u is the LOCAL k-pair unit (0..47): global k-pair = 64q + u.
#define INIT_W(u) { \
    const float2 wa = *(const float2*)(wrq + (2 * (u)) * HID); \
    const float2 wb = *(const float2*)(wrq + (2 * (u) + 1) * HID); \
    W##u##_0 = pk2(wa.x, wb.x); \
    W##u##_1 = pk2(wa.y, wb.y); }

#define FMAW(u, i2) { const f16x2 hh_##u = hu.h2[i2]; \
    a0 = __builtin_elementwise_fma(hh_##u, W##u##_0, a0); \
    a1 = __builtin_elementwise_fma(hh_##u, W##u##_1, a1); }

#define GROUPR(i, u0,u1,u2,u3) { \
    union { uint4 v; f16x2 h2[4]; } hu; \
    hu.v = hb4[qb ^ (i)]; \
    FMAW(u0,0) FMAW(u1,1) FMAW(u2,2) FMAW(u3,3) }

__global__ __launch_bounds__(1024)
void k2_rnn(const float* __restrict__ wr, float* __restrict__ out) {
  extern __shared__ char smem[];
  uint4* w4           = (uint4*)smem;                       // 8 planes x 1024 = 128KB
  f16x2 (*hbuf)[256]  = (f16x2(*)[256])(smem + 131072);     // 2 x 64 uint4 lines = 2KB

  const int tid = threadIdx.x;
  const int q   = tid & 3;        // k-slice: k in [128q, 128q+128)
  const int jj  = tid >> 2;       // 0..255
  const int c0  = 2 * jj;         // owned column pair c0, c0+1
  const int b   = blockIdx.x;
  const int qb  = q * 17;         // swizzled line base: (q<<4)|q

  const float* wrq = wr + (long)(128 * q) * HID + c0;

  DECL_W(0)  DECL_W(1)  DECL_W(2)  DECL_W(3)  DECL_W(4)  DECL_W(5)
  DECL_W(6)  DECL_W(7)  DECL_W(8)  DECL_W(9)  DECL_W(10) DECL_W(11)
  DECL_W(12) DECL_W(13) DECL_W(14) DECL_W(15) DECL_W(16) DECL_W(17)
  DECL_W(18) DECL_W(19) DECL_W(20) DECL_W(21) DECL_W(22) DECL_W(23)
  DECL_W(24) DECL_W(25) DECL_W(26) DECL_W(27) DECL_W(28) DECL_W(29)
  DECL_W(30) DECL_W(31) DECL_W(32) DECL_W(33) DECL_W(34) DECL_W(35)
  DECL_W(36) DECL_W(37) DECL_W(38) DECL_W(39) DECL_W(40) DECL_W(41)
  DECL_W(42) DECL_W(43) DECL_W(44) DECL_W(45) DECL_W(46) DECL_W(47)

  INIT_W(0)  INIT_W(1)  INIT_W(2)  INIT_W(3)  INIT_W(4)  INIT_W(5)
  INIT_W(6)  INIT_W(7)  INIT_W(8)  INIT_W(9)  INIT_W(10) INIT_W(11)
  INIT_W(12) INIT_W(13) INIT_W(14) INIT_W(15) INIT_W(16) INIT_W(17)
  INIT_W(18) INIT_W(19) INIT_W(20) INIT_W(21) INIT_W(22) INIT_W(23)
  INIT_W(24) INIT_W(25) INIT_W(26) INIT_W(27) INIT_W(28) INIT_W(29)
  INIT_W(30) INIT_W(31) INIT_W(32) INIT_W(33) INIT_W(34) INIT_W(35)
  INIT_W(36) INIT_W(37) INIT_W(38) INIT_W(39) INIT_W(40) INIT_W(41)
  INIT_W(42) INIT_W(43) INIT_W(44) INIT_W(45) INIT_W(46) INIT_W(47)

  // ---- LDS weight cache: local units u in [48,64), self-owned slots.
  // plane p = 2*g + colsel, g = (u-48)/4; w4[p*1024 + tid].
  #pragma unroll
  for (int g = 0; g < 4; ++g) {
    union { uint4 v; f16x2 h2[4]; } h2a, h2b;
    #pragma unroll
    for (int i = 0; i < 4; ++i) {
      const int u = 48 + 4 * g + i;
      const float2 wa = *(const float2*)(wrq + (2 * u) * HID);
      const float2 wb = *(const float2*)(wrq + (2 * u + 1) * HID);
      h2a.h2[i] = pk2(wa.x, wb.x);
      h2b.h2[i] = pk2(wa.y, wb.y);
    }
    w4[(2 * g + 0) * 1024 + tid] = h2a.v;
    w4[(2 * g + 1) * 1024 + tid] = h2b.v;
  }

  const f16x2 Z2 = {(f16)0.f, (f16)0.f};
  if (tid < 256) { hbuf[0][tid] = Z2; hbuf[1][tid] = Z2; }
  __syncthreads();

  // owner lanes (q < 2) handle column cme = c0 + q
  const int cme = c0 + q;
  // physical f16 slot of column cme in the line-swizzled hbuf
  const int Lg   = cme >> 3;
  const int Lp   = (Lg & 48) | ((Lg ^ (Lg >> 4)) & 15);
  const int hpos = Lp * 8 + (cme & 7);

  float h  = 0.0f;
  float av = (q < 2) ? out[(long)b * HID + cme] : 0.0f;   // A[0] prefetch

  const uint4* w4t = w4 + tid;

  #pragma unroll 1
  for (int t = 0; t < SEQ; ++t) {
    const int cur = t & 1;
    const int nxt = cur ^ 1;
    const long aofs = ((long)t * BATCH + b) * HID;
    const int tn = (t + 1 < SEQ) ? (t + 1) : (SEQ - 1);
    const float av_next = (q < 2) ? out[((long)tn * BATCH + b) * HID + cme] : 0.0f;

    const uint4* hb4 = (const uint4*)&hbuf[cur][0];
    f16x2 a0 = Z2, a1 = Z2;

    // register-weight part: local units 0..47
    GROUPR(0,  0, 1, 2, 3)   GROUPR(1,  4, 5, 6, 7)
    GROUPR(2,  8, 9,10,11)   GROUPR(3, 12,13,14,15)
    GROUPR(4, 16,17,18,19)   GROUPR(5, 20,21,22,23)
    GROUPR(6, 24,25,26,27)   GROUPR(7, 28,29,30,31)
    GROUPR(8, 32,33,34,35)   GROUPR(9, 36,37,38,39)
    GROUPR(10,40,41,42,43)   GROUPR(11,44,45,46,47)

    // LDS-weight part: local units 48..63, conflict-free self-reads
    #pragma unroll
    for (int g = 0; g < 4; ++g) {
      union { uint4 v; f16x2 h2[4]; } hu;
      hu.v = hb4[qb ^ (12 + g)];
      union { uint4 v; f16x2 h2[4]; } w0, w1;
      w0.v = w4t[(2 * g + 0) * 1024];
      w1.v = w4t[(2 * g + 1) * 1024];
      #pragma unroll
      for (int i = 0; i < 4; ++i) {
        const f16x2 hh = hu.h2[i];
        a0 = __builtin_elementwise_fma(hh, w0.h2[i], a0);
        a1 = __builtin_elementwise_fma(hh, w1.h2[i], a1);
      }
    }

    // reduce the 4 k-slices across the quad (lanes differ in bits 0..1)
    float y0 = (float)a0[0] + (float)a0[1];
    float y1 = (float)a1[0] + (float)a1[1];
    y0 += __shfl_xor(y0, 1); y0 += __shfl_xor(y0, 2);
    y1 += __shfl_xor(y1, 1); y1 += __shfl_xor(y1, 2);

    if (q < 2) {
      const float y   = (q == 0) ? y0 : y1;
      const float arg = av + y;
      const float e   = __expf(2.0f * arg);
      const float th  = 1.0f - 2.0f / (e + 1.0f);
      h += INV_TAU * (th - h);

      out[aofs + cme] = h;
      ((f16*)hbuf[nxt])[hpos] = (f16)h;
      av = av_next;
    }
    __syncthreads();
  }
}

// ---------------------------------------------------------------------------
extern "C" void kernel_launch(void* const* d_in, const int* in_sizes, int n_in,
                              void* d_out, int out_size, void* d_ws, size_t ws_size,
                              hipStream_t stream) {
  const float* x    = (const float*)d_in[0];
  const float* win  = (const float*)d_in[1];
  const float* wr   = (const float*)d_in[2];
  const float* bias = (const float*)d_in[3];
  float* out = (float*)d_out;

  (void)d_ws; (void)ws_size; (void)in_sizes; (void)n_in; (void)out_size;

  (void)hipFuncSetAttribute((const void*)k2_rnn,
                            hipFuncAttributeMaxDynamicSharedMemorySize, K2_SMEM);

  k1_gemm<<<dim3((SEQ * BATCH) / 64), dim3(512), 0, stream>>>(x, win, bias, out);
  k2_rnn<<<dim3(BATCH), dim3(1024), K2_SMEM, stream>>>(wr, out);
}